// Round 3
// baseline (847.710 us; speedup 1.0000x reference)
//
#include <hip/hip_runtime.h>
#include <stdint.h>

typedef __bf16 bf16_t;
typedef __bf16 bf16x8 __attribute__((ext_vector_type(8)));
typedef __bf16 bf16x4 __attribute__((ext_vector_type(4)));
typedef float  f32x4  __attribute__((ext_vector_type(4)));

constexpr int cBS = 64, cP = 512, cD = 1024, cDWM = 1024, cH = 16, cHD = 64, cW = 128;
constexpr int cVTP = 672;           // padded p-extent of Vt (sp = p + 128, max used 656)
constexpr int cM = cBS * cP;        // 32768
constexpr float cSCALE = 0.125f;    // 1/sqrt(64)

__device__ __forceinline__ void gld_lds16(const void* g, void* l) {
#if __has_builtin(__builtin_amdgcn_global_load_lds)
  __builtin_amdgcn_global_load_lds(
      (__attribute__((address_space(1))) void*)g,
      (__attribute__((address_space(3))) void*)l, 16, 0, 0);
#else
  *(bf16x8*)l = *(const bf16x8*)g;
#endif
}

// ---------------------------------------------------------------------------
// fp32 -> bf16 conversion of X
__global__ void cvt_x_k(const float* __restrict__ X, bf16_t* __restrict__ Y, int n) {
  int i = (blockIdx.x * blockDim.x + threadIdx.x) * 4;
  if (i >= n) return;
  float4 v = *(const float4*)(X + i);
  bf16x4 o;
  o[0] = (bf16_t)v.x; o[1] = (bf16_t)v.y; o[2] = (bf16_t)v.z; o[3] = (bf16_t)v.w;
  *(bf16x4*)(Y + i) = o;
}

// transpose + convert the four 1024x1024 weights: W[k][n] fp32 -> Wt[n][k] bf16
__global__ void cvt_wt_k(const float* __restrict__ W0, const float* __restrict__ W1,
                         const float* __restrict__ W2, const float* __restrict__ W3,
                         bf16_t* __restrict__ T0, bf16_t* __restrict__ T1,
                         bf16_t* __restrict__ T2, bf16_t* __restrict__ T3) {
  __shared__ float tile[32][33];
  const float* Wsrc; bf16_t* Tdst;
  switch (blockIdx.z) {
    case 0: Wsrc = W0; Tdst = T0; break;
    case 1: Wsrc = W1; Tdst = T1; break;
    case 2: Wsrc = W2; Tdst = T2; break;
    default: Wsrc = W3; Tdst = T3; break;
  }
  const int n0 = blockIdx.x * 32, k0 = blockIdx.y * 32;
  const int c = threadIdx.x & 31, r8 = threadIdx.x >> 5;
#pragma unroll
  for (int q = 0; q < 4; ++q) {
    int row = r8 + q * 8;
    tile[row][c] = Wsrc[(size_t)(k0 + row) * 1024 + n0 + c];
  }
  __syncthreads();
#pragma unroll
  for (int q = 0; q < 4; ++q) {
    int row = r8 + q * 8;
    Tdst[(size_t)(n0 + row) * 1024 + k0 + c] = (bf16_t)tile[c][row];
  }
}

// r[b][t] = index of last reset at-or-before t (0 if none): parallel max-scan
__global__ void resets2_k(const int* __restrict__ mask, int* __restrict__ r) {
  __shared__ int sm[cP];
  const int b = blockIdx.x, t = threadIdx.x;
  sm[t] = mask[b * cP + t] ? t : 0;
  __syncthreads();
#pragma unroll
  for (int d = 1; d < cP; d <<= 1) {
    int u = (t >= d) ? sm[t - d] : 0;
    __syncthreads();
    if (u > sm[t]) sm[t] = u;
    __syncthreads();
  }
  r[b * cP + t] = sm[t];
}

// ---------------------------------------------------------------------------
// 256x256 GEMM core, quadrant-software-pipelined with sched_group_barrier
// enforcement (T19 as pipeline-creator, not graft):
//   BM=BN=256, BK=64, 512 threads = 8 waves (2Mx4N), per-wave 128x64 out.
//   Per K-tile emission order (pinned by the directive chain):
//     [16 ds_read: A0-3 + B0-3 frags] [8 global_load_lds: next tile]
//     [16 MFMA q0] [8 ds_read: A4-7] [16 MFMA q1] [32 MFMA q2+q3]
//     vmcnt(0); barrier
//   Reads get a full MFMA cluster of slack -> compiler-counted lgkm waits are
//   short; LDS pipe drains under the MFMA pipe instead of alternating.
//   LDS XOR swizzle (16B group ^ row&7): bank-conflict-free (verified r1: 0).
#define MFMA_B16(a, b, c) c = __builtin_amdgcn_mfma_f32_16x16x32_bf16(a, b, c, 0, 0, 0)

template <int NBLK>
__device__ __forceinline__ void gemm256_core(const bf16_t* __restrict__ A,
                                             const bf16_t* __restrict__ Bt,
                                             f32x4 (&acc)[8][4],
                                             int& m0_out, int& n0_out) {
  constexpr int K = 1024;
  __shared__ __align__(16) bf16_t As[2][256 * 64];
  __shared__ __align__(16) bf16_t Bs[2][256 * 64];
  const int tid = threadIdx.x;
  const int wid = tid >> 6, ln = tid & 63;
  const int ln15 = ln & 15, g4 = ln >> 4;
  const int wr = wid >> 2, wc = wid & 3;

  // XCD-aware swizzle: grid = 8 XCDs x 16 m-blocks x NBLK n-blocks, n-fastest
  const int g = blockIdx.x;
  const int xcd = g & 7, s = g >> 3;
  const int nb = s % NBLK, mloc = s / NBLK;
  const int m0 = (xcd * 16 + mloc) * 256, n0 = nb * 256;
  m0_out = m0; n0_out = n0;

  const bf16_t* Ag = A + (size_t)m0 * K;
  const bf16_t* Bg = Bt + (size_t)n0 * K;

  // Stage addressing: 8 (half,l) slots; LDS dest linear (global_load_lds
  // rule), swizzle applied on the per-lane GLOBAL source group.
  const bf16_t* gsrc[8];
  bf16_t* ldst[8];
#pragma unroll
  for (int sl = 0; sl < 8; ++sl) {
    const int hh = sl >> 1, l = sl & 1;
    const int E = ((hh & 1) << 13) | (l << 12) | (tid << 3);
    const int row = E >> 6;
    const int cg = ((E >> 3) & 7) ^ (row & 7);
    gsrc[sl] = ((hh < 2) ? Ag : Bg) + (size_t)row * K + cg * 8;
    ldst[sl] = ((hh < 2) ? &As[0][0] : &Bs[0][0]) + E;
  }

  // Fragment-read bases; row&7 == ln15&7 (i*16 ≡ 0 mod 8)
  const int rA = wr * 128 + ln15;
  const int rB = wc * 64 + ln15;
  const int sA0 = ((g4 ^ (ln15 & 7)) << 3), sA1 = (((4 | g4) ^ (ln15 & 7)) << 3);
  const bf16_t* pA = &As[0][rA * 64];
  const bf16_t* pB = &Bs[0][rB * 64];

#pragma unroll
  for (int i = 0; i < 8; ++i)
#pragma unroll
    for (int j = 0; j < 4; ++j) acc[i][j] = {0.f, 0.f, 0.f, 0.f};

  // Prologue: stage tile 0 into buf 0, drain, sync.
#pragma unroll
  for (int sl = 0; sl < 8; ++sl) gld_lds16(gsrc[sl], ldst[sl]);
  asm volatile("s_waitcnt vmcnt(0)" ::: "memory");
  __builtin_amdgcn_sched_barrier(0);
  __builtin_amdgcn_s_barrier();

  bf16x8 afr[8][2], bfr[4][2];

#pragma unroll 2
  for (int kt = 0; kt < 16; ++kt) {
    const int bo = (kt & 1) << 14;               // buf element offset (16384)
    // Last iteration stages a dummy (re-reads tile 15 into the dead buffer)
    // so the instruction counts per scheduling region are constant.
    const int k0n = ((kt < 15) ? kt + 1 : 15) << 6;
    const int bon = ((kt + 1) & 1) << 14;
    const bf16_t* pAb = pA + bo;
    const bf16_t* pBb = pB + bo;

    // R0+R1: q0/q1 fragments (16 ds_read_b128)
#pragma unroll
    for (int i = 0; i < 4; ++i) {
      afr[i][0] = *(const bf16x8*)(pAb + i * 1024 + sA0);
      afr[i][1] = *(const bf16x8*)(pAb + i * 1024 + sA1);
    }
#pragma unroll
    for (int j = 0; j < 4; ++j) {
      bfr[j][0] = *(const bf16x8*)(pBb + j * 1024 + sA0);
      bfr[j][1] = *(const bf16x8*)(pBb + j * 1024 + sA1);
    }

    // Stage next tile (8 global_load_lds)
#pragma unroll
    for (int sl = 0; sl < 8; ++sl) gld_lds16(gsrc[sl] + k0n, ldst[sl] + bon);

    // q0: mh0 x n01
    __builtin_amdgcn_s_setprio(1);
#pragma unroll
    for (int i = 0; i < 4; ++i)
#pragma unroll
      for (int j = 0; j < 2; ++j) {
        MFMA_B16(afr[i][0], bfr[j][0], acc[i][j]);
        MFMA_B16(afr[i][1], bfr[j][1], acc[i][j]);
      }
    __builtin_amdgcn_s_setprio(0);

    // R2: A mh1 fragments (8 ds_read_b128)
#pragma unroll
    for (int i = 4; i < 8; ++i) {
      afr[i][0] = *(const bf16x8*)(pAb + i * 1024 + sA0);
      afr[i][1] = *(const bf16x8*)(pAb + i * 1024 + sA1);
    }

    // q1: mh0 x n23
    __builtin_amdgcn_s_setprio(1);
#pragma unroll
    for (int i = 0; i < 4; ++i)
#pragma unroll
      for (int j = 2; j < 4; ++j) {
        MFMA_B16(afr[i][0], bfr[j][0], acc[i][j]);
        MFMA_B16(afr[i][1], bfr[j][1], acc[i][j]);
      }
    // q2: mh1 x n23, q3: mh1 x n01
#pragma unroll
    for (int i = 4; i < 8; ++i)
#pragma unroll
      for (int j = 2; j < 4; ++j) {
        MFMA_B16(afr[i][0], bfr[j][0], acc[i][j]);
        MFMA_B16(afr[i][1], bfr[j][1], acc[i][j]);
      }
#pragma unroll
    for (int i = 4; i < 8; ++i)
#pragma unroll
      for (int j = 0; j < 2; ++j) {
        MFMA_B16(afr[i][0], bfr[j][0], acc[i][j]);
        MFMA_B16(afr[i][1], bfr[j][1], acc[i][j]);
      }
    __builtin_amdgcn_s_setprio(0);

    // Directive chain: pin the emission order of this scheduling region.
    // Masks (m137): DS_READ=0x100, MFMA=0x8, VMEM_READ=0x20.
    __builtin_amdgcn_sched_group_barrier(0x100, 16, 0);  // q0/q1 frag reads
    __builtin_amdgcn_sched_group_barrier(0x020,  8, 0);  // next-tile stage
    __builtin_amdgcn_sched_group_barrier(0x008, 16, 0);  // MFMA q0
    __builtin_amdgcn_sched_group_barrier(0x100,  8, 0);  // A-mh1 frag reads
    __builtin_amdgcn_sched_group_barrier(0x008, 16, 0);  // MFMA q1
    __builtin_amdgcn_sched_group_barrier(0x008, 32, 0);  // MFMA q2+q3

    // Tile end: next tile landed (issue-to-drain = nearly a full tile);
    // all frag reads retired (their waits precede q2/q3 MFMAs).
    asm volatile("s_waitcnt vmcnt(0)" ::: "memory");
    __builtin_amdgcn_sched_barrier(0);
    __builtin_amdgcn_s_barrier();
  }
}

// Fused QKV projection: C[32768][3072] = Xbf * Wqkv^T. Segment (1024-col) 0->Q
// head-major, 1->K head-major, 2->Vt transposed layout.
__global__ __launch_bounds__(512, 2)
void gemm_qkv3_k(const bf16_t* __restrict__ A, const bf16_t* __restrict__ Wt,
                 const float* __restrict__ bq, const float* __restrict__ bk,
                 const float* __restrict__ bvv,
                 bf16_t* __restrict__ Qh, bf16_t* __restrict__ Kh,
                 bf16_t* __restrict__ Vt) {
  f32x4 acc[8][4];
  int m0, n0;
  gemm256_core<12>(A, Wt, acc, m0, n0);

  const int tid = threadIdx.x;
  const int wid = tid >> 6, ln = tid & 63;
  const int ln15 = ln & 15, g4 = ln >> 4;
  const int wr = wid >> 2, wc = wid & 3;

  const int seg = n0 >> 10;                      // block-uniform: 0=Q 1=K 2=V
  const float* bias = (seg == 0) ? bq : (seg == 1) ? bk : bvv;
  bf16_t* QK = (seg == 0) ? Qh : Kh;
#pragma unroll
  for (int i = 0; i < 8; ++i) {
    const int rbase = m0 + wr * 128 + i * 16 + g4 * 4;
    const int b = rbase >> 9, pb = rbase & 511;
#pragma unroll
    for (int j = 0; j < 4; ++j) {
      const int col = n0 + wc * 64 + j * 16 + ln15;
      const int cl = col & 1023;
      const int h = cl >> 6, hd = cl & 63;
      const float bv = bias[cl];
      if (seg < 2) {
        // head-major: [b][h][p][hd]
#pragma unroll
        for (int r = 0; r < 4; ++r)
          QK[(((size_t)(b * cH + h)) * cP + pb + r) * cHD + hd] =
              (bf16_t)(acc[i][j][r] + bv);
      } else {
        bf16x4 pk;
#pragma unroll
        for (int r = 0; r < 4; ++r) pk[r] = (bf16_t)(acc[i][j][r] + bv);
        *(bf16x4*)(Vt + ((size_t)((b * cH + h) * cHD + hd)) * cVTP + 128 + pb) = pk;
      }
    }
  }
}

// Output projection: C[32768][1024] fp32 = Ob * Wot^T + bo
__global__ __launch_bounds__(512, 2)
void gemm_bt3_k(const bf16_t* __restrict__ A, const bf16_t* __restrict__ Bt,
                const float* __restrict__ bias, float* __restrict__ C) {
  f32x4 acc[8][4];
  int m0, n0;
  gemm256_core<4>(A, Bt, acc, m0, n0);

  const int tid = threadIdx.x;
  const int wid = tid >> 6, ln = tid & 63;
  const int ln15 = ln & 15, g4 = ln >> 4;
  const int wr = wid >> 2, wc = wid & 3;

#pragma unroll
  for (int i = 0; i < 8; ++i) {
    const int rbase = m0 + wr * 128 + i * 16 + g4 * 4;
#pragma unroll
    for (int j = 0; j < 4; ++j) {
      const int col = n0 + wc * 64 + j * 16 + ln15;
      const float bv = bias[col];
#pragma unroll
      for (int r = 0; r < 4; ++r)
        C[(size_t)(rbase + r) * cD + col] = acc[i][j][r] + bv;
    }
  }
}

// ---------------------------------------------------------------------------
// Windowed attention v3: block = (head, batch, t-chunk); 4 waves each own a
// 16-token tile; 2 iterations cover the 128-token chunk. Q/K head-major.
__global__ __launch_bounds__(256)
void attn3_k(const bf16_t* __restrict__ Q, const bf16_t* __restrict__ Kv,
             const bf16_t* __restrict__ Vt, const int* __restrict__ rr,
             bf16_t* __restrict__ O) {
  __shared__ __align__(16) bf16_t Pl[4][16][168];
  const int tid = threadIdx.x;
  const int wv = tid >> 6, ln = tid & 63, ln15 = ln & 15, g4 = ln >> 4;
  const int h = blockIdx.x, b = blockIdx.y, tc = blockIdx.z;
  bf16_t(*Pw)[168] = Pl[wv];
  const bf16_t* vb = Vt + ((size_t)(b * cH + h)) * cHD * cVTP;
  const bf16_t* qb = Q + ((size_t)(b * cH + h)) * cP * cHD;
  const bf16_t* kb = Kv + ((size_t)(b * cH + h)) * cP * cHD;

  for (int sub = 0; sub < 2; ++sub) {
    const int t0 = (tc * 2 + sub) * 64 + wv * 16;
    const int sbase = t0 - 128;

    int rv[4];
#pragma unroll
    for (int r = 0; r < 4; ++r) rv[r] = rr[b * cP + t0 + g4 * 4 + r];

    // Q A-frag: m = ln15 (t), k = g4*8+j (hd)
    const bf16_t* qp = qb + (size_t)(t0 + ln15) * cHD + g4 * 8;
    const bf16x8 qa0 = *(const bf16x8*)qp;
    const bf16x8 qa1 = *(const bf16x8*)(qp + 32);

    // QK^T over 9 s-chunks of 16 (s in [t0-128, t0+15])
    f32x4 lg[9];
#pragma unroll
    for (int c = 0; c < 9; ++c) {
      const int s = sbase + c * 16 + ln15;  // B-frag n = ln15 (s), k = hd
      bf16x8 k0v, k1v;
      if ((unsigned)s < (unsigned)cP) {
        const bf16_t* kp = kb + (size_t)s * cHD + g4 * 8;
        k0v = *(const bf16x8*)kp;
        k1v = *(const bf16x8*)(kp + 32);
      } else {
#pragma unroll
        for (int z = 0; z < 8; ++z) { k0v[z] = (bf16_t)0.f; k1v[z] = (bf16_t)0.f; }
      }
      f32x4 a = {0.f, 0.f, 0.f, 0.f};
      a = __builtin_amdgcn_mfma_f32_16x16x32_bf16(qa0, k0v, a, 0, 0, 0);
      a = __builtin_amdgcn_mfma_f32_16x16x32_bf16(qa1, k1v, a, 0, 0, 0);
      lg[c] = a;
    }

    // mask + scale; C layout: col(s)=ln15, row(t)=g4*4+reg
    float mx[4] = {-1e30f, -1e30f, -1e30f, -1e30f};
#pragma unroll
    for (int c = 0; c < 9; ++c)
#pragma unroll
      for (int r = 0; r < 4; ++r) {
        const int s = sbase + c * 16 + ln15;
        const int t = t0 + g4 * 4 + r;
        const bool ok = (s >= rv[r]) && (s <= t) && (t - s < cW);
        const float l = ok ? lg[c][r] * cSCALE : -1e30f;
        lg[c][r] = l;
        mx[r] = fmaxf(mx[r], l);
      }
#pragma unroll
    for (int r = 0; r < 4; ++r) {
      mx[r] = fmaxf(mx[r], __shfl_xor(mx[r], 1));
      mx[r] = fmaxf(mx[r], __shfl_xor(mx[r], 2));
      mx[r] = fmaxf(mx[r], __shfl_xor(mx[r], 4));
      mx[r] = fmaxf(mx[r], __shfl_xor(mx[r], 8));
    }
    float sm[4] = {0.f, 0.f, 0.f, 0.f};
#pragma unroll
    for (int c = 0; c < 9; ++c)
#pragma unroll
      for (int r = 0; r < 4; ++r) {
        const float e = __expf(lg[c][r] - mx[r]);
        lg[c][r] = e;
        sm[r] += e;
      }
#pragma unroll
    for (int r = 0; r < 4; ++r) {
      sm[r] += __shfl_xor(sm[r], 1);
      sm[r] += __shfl_xor(sm[r], 2);
      sm[r] += __shfl_xor(sm[r], 4);
      sm[r] += __shfl_xor(sm[r], 8);
    }
    float inv[4];
#pragma unroll
    for (int r = 0; r < 4; ++r) inv[r] = 1.f / sm[r];

    // P -> LDS (C-layout write), zero pad cols 144..159 for the 5th PV chunk
#pragma unroll
    for (int c = 0; c < 9; ++c)
#pragma unroll
      for (int r = 0; r < 4; ++r)
        Pw[g4 * 4 + r][c * 16 + ln15] = (bf16_t)(lg[c][r] * inv[r]);
#pragma unroll
    for (int z = 0; z < 4; ++z)
      Pw[ln15][144 + g4 * 4 + z] = (bf16_t)0.f;

    // PV: A = P (m=t, k=s from LDS), B = Vt rows (n=hd, k=s contiguous)
    f32x4 oacc[4];
#pragma unroll
    for (int j = 0; j < 4; ++j) oacc[j] = {0.f, 0.f, 0.f, 0.f};
#pragma unroll
    for (int c2 = 0; c2 < 5; ++c2) {
      const bf16x8 pa = *(const bf16x8*)(&Pw[ln15][c2 * 32 + g4 * 8]);
#pragma unroll
      for (int j = 0; j < 4; ++j) {
        const bf16x8 vf =
            *(const bf16x8*)(vb + (size_t)(j * 16 + ln15) * cVTP + (t0 + c2 * 32 + g4 * 8));
        oacc[j] = __builtin_amdgcn_mfma_f32_16x16x32_bf16(pa, vf, oacc[j], 0, 0, 0);
      }
    }
#pragma unroll
    for (int j = 0; j < 4; ++j) {
      const int col = h * cHD + j * 16 + ln15;
#pragma unroll
      for (int r = 0; r < 4; ++r)
        O[((size_t)(b * cP + t0 + g4 * 4 + r)) * cDWM + col] = (bf16_t)oacc[j][r];
    }
  }
}

// ---------------------------------------------------------------------------
extern "C" void kernel_launch(void* const* d_in, const int* in_sizes, int n_in,
                              void* d_out, int out_size, void* d_ws, size_t ws_size,
                              hipStream_t stream) {
  (void)in_sizes; (void)n_in; (void)out_size; (void)ws_size;
  const float* x  = (const float*)d_in[0];
  const int* mask = (const int*)d_in[1];
  const float* Wq = (const float*)d_in[2];
  const float* bq = (const float*)d_in[3];
  const float* Wk = (const float*)d_in[4];
  const float* bk = (const float*)d_in[5];
  const float* Wv = (const float*)d_in[6];
  const float* bv = (const float*)d_in[7];
  const float* Wo = (const float*)d_in[8];
  const float* bo = (const float*)d_in[9];
  float* out = (float*)d_out;

  char* ws = (char*)d_ws;
  size_t off = 0;
  bf16_t* Xbf = (bf16_t*)(ws + off); off += (size_t)cM * cD * 2;          // 64 MiB
  bf16_t* Wqt = (bf16_t*)(ws + off); off += (size_t)cD * cDWM * 2;        // contiguous
  bf16_t* Wkt = (bf16_t*)(ws + off); off += (size_t)cD * cDWM * 2;        //   [3072][1024]
  bf16_t* Wvt = (bf16_t*)(ws + off); off += (size_t)cD * cDWM * 2;        //   QKV block
  bf16_t* Wot = (bf16_t*)(ws + off); off += (size_t)cDWM * cD * 2;
  bf16_t* Qh  = (bf16_t*)(ws + off); off += (size_t)cM * cDWM * 2;        // 64 MiB
  bf16_t* Kh  = (bf16_t*)(ws + off); off += (size_t)cM * cDWM * 2;        // 64 MiB
  bf16_t* Vt  = (bf16_t*)(ws + off); off += (size_t)cBS * cH * cHD * cVTP * 2;  // 84 MiB
  int* rbuf   = (int*)(ws + off);    off += (size_t)cBS * cP * 4;
  bf16_t* Ob  = Xbf;  // X no longer needed after the QKV projection

  cvt_x_k<<<(cM * cD / 4 + 255) / 256, 256, 0, stream>>>(x, Xbf, cM * cD);
  cvt_wt_k<<<dim3(32, 32, 4), 256, 0, stream>>>(Wq, Wk, Wv, Wo, Wqt, Wkt, Wvt, Wot);
  resets2_k<<<cBS, cP, 0, stream>>>(mask, rbuf);

  // 8 XCD x 16 m-blocks x 12 n-blocks = 1536 workgroups of 512
  gemm_qkv3_k<<<dim3(1536), 512, 0, stream>>>(Xbf, Wqt, bq, bk, bv, Qh, Kh, Vt);

  attn3_k<<<dim3(cH, cBS, 4), 256, 0, stream>>>(Qh, Kh, Vt, rbuf, Ob);

  // 8 XCD x 16 m-blocks x 4 n-blocks = 512 workgroups of 512
  gemm_bt3_k<<<dim3(512), 512, 0, stream>>>(Ob, Wot, bo, out);
}

// Round 4
// 705.324 us; speedup vs baseline: 1.2019x; 1.2019x over previous
//
#include <hip/hip_runtime.h>
#include <stdint.h>

typedef __bf16 bf16_t;
typedef __bf16 bf16x8 __attribute__((ext_vector_type(8)));
typedef __bf16 bf16x4 __attribute__((ext_vector_type(4)));
typedef float  f32x4  __attribute__((ext_vector_type(4)));

constexpr int cBS = 64, cP = 512, cD = 1024, cDWM = 1024, cH = 16, cHD = 64, cW = 128;
constexpr int cVTP = 672;           // padded p-extent of Vt (sp = p + 128, max used 656)
constexpr int cM = cBS * cP;        // 32768
constexpr float cSCALE = 0.125f;    // 1/sqrt(64)

__device__ __forceinline__ void gld_lds16(const void* g, void* l) {
#if __has_builtin(__builtin_amdgcn_global_load_lds)
  __builtin_amdgcn_global_load_lds(
      (__attribute__((address_space(1))) void*)g,
      (__attribute__((address_space(3))) void*)l, 16, 0, 0);
#else
  *(bf16x8*)l = *(const bf16x8*)g;
#endif
}

// ---------------------------------------------------------------------------
// fp32 -> bf16 conversion of X
__global__ void cvt_x_k(const float* __restrict__ X, bf16_t* __restrict__ Y, int n) {
  int i = (blockIdx.x * blockDim.x + threadIdx.x) * 4;
  if (i >= n) return;
  float4 v = *(const float4*)(X + i);
  bf16x4 o;
  o[0] = (bf16_t)v.x; o[1] = (bf16_t)v.y; o[2] = (bf16_t)v.z; o[3] = (bf16_t)v.w;
  *(bf16x4*)(Y + i) = o;
}

// transpose + convert the four 1024x1024 weights: W[k][n] fp32 -> Wt[n][k] bf16
__global__ void cvt_wt_k(const float* __restrict__ W0, const float* __restrict__ W1,
                         const float* __restrict__ W2, const float* __restrict__ W3,
                         bf16_t* __restrict__ T0, bf16_t* __restrict__ T1,
                         bf16_t* __restrict__ T2, bf16_t* __restrict__ T3) {
  __shared__ float tile[32][33];
  const float* Wsrc; bf16_t* Tdst;
  switch (blockIdx.z) {
    case 0: Wsrc = W0; Tdst = T0; break;
    case 1: Wsrc = W1; Tdst = T1; break;
    case 2: Wsrc = W2; Tdst = T2; break;
    default: Wsrc = W3; Tdst = T3; break;
  }
  const int n0 = blockIdx.x * 32, k0 = blockIdx.y * 32;
  const int c = threadIdx.x & 31, r8 = threadIdx.x >> 5;
#pragma unroll
  for (int q = 0; q < 4; ++q) {
    int row = r8 + q * 8;
    tile[row][c] = Wsrc[(size_t)(k0 + row) * 1024 + n0 + c];
  }
  __syncthreads();
#pragma unroll
  for (int q = 0; q < 4; ++q) {
    int row = r8 + q * 8;
    Tdst[(size_t)(n0 + row) * 1024 + k0 + c] = (bf16_t)tile[c][row];
  }
}

// r[b][t] = index of last reset at-or-before t (0 if none): parallel max-scan
__global__ void resets2_k(const int* __restrict__ mask, int* __restrict__ r) {
  __shared__ int sm[cP];
  const int b = blockIdx.x, t = threadIdx.x;
  sm[t] = mask[b * cP + t] ? t : 0;
  __syncthreads();
#pragma unroll
  for (int d = 1; d < cP; d <<= 1) {
    int u = (t >= d) ? sm[t - d] : 0;
    __syncthreads();
    if (u > sm[t]) sm[t] = u;
    __syncthreads();
  }
  r[b * cP + t] = sm[t];
}

// ---------------------------------------------------------------------------
// 256x256 GEMM core (r2 version — measured 264 us on the QKV shape):
//   BM=BN=256, BK=64, 512 threads = 8 waves (2Mx4N), per-wave 128x64 out.
//   ONE barrier per K-tile; whole next tile prefetched into buf^1 (depth-1);
//   fragment reads in two batches interleaved with MFMA quadrants; compiler
//   inserts counted lgkmcnt waits. LDS XOR swizzle: bank-conflict-free.
#define MFMA_B16(a, b, c) c = __builtin_amdgcn_mfma_f32_16x16x32_bf16(a, b, c, 0, 0, 0)

template <int NBLK>
__device__ __forceinline__ void gemm256_core(const bf16_t* __restrict__ A,
                                             const bf16_t* __restrict__ Bt,
                                             f32x4 (&acc)[8][4],
                                             int& m0_out, int& n0_out) {
  constexpr int K = 1024;
  __shared__ __align__(16) bf16_t As[2][256 * 64];
  __shared__ __align__(16) bf16_t Bs[2][256 * 64];
  const int tid = threadIdx.x;
  const int wid = tid >> 6, ln = tid & 63;
  const int ln15 = ln & 15, g4 = ln >> 4;
  const int wr = wid >> 2, wc = wid & 3;

  // XCD-aware swizzle: grid = 8 XCDs x 16 m-blocks x NBLK n-blocks, n-fastest
  const int g = blockIdx.x;
  const int xcd = g & 7, s = g >> 3;
  const int nb = s % NBLK, mloc = s / NBLK;
  const int m0 = (xcd * 16 + mloc) * 256, n0 = nb * 256;
  m0_out = m0; n0_out = n0;

  const bf16_t* Ag = A + (size_t)m0 * K;
  const bf16_t* Bg = Bt + (size_t)n0 * K;

  // Stage addressing: 8 (half,l) slots; LDS dest linear (global_load_lds
  // rule), swizzle applied on the per-lane GLOBAL source group.
  const bf16_t* gsrc[8];
  bf16_t* ldst[8];
#pragma unroll
  for (int sl = 0; sl < 8; ++sl) {
    const int hh = sl >> 1, l = sl & 1;
    const int E = ((hh & 1) << 13) | (l << 12) | (tid << 3);
    const int row = E >> 6;
    const int cg = ((E >> 3) & 7) ^ (row & 7);
    gsrc[sl] = ((hh < 2) ? Ag : Bg) + (size_t)row * K + cg * 8;
    ldst[sl] = ((hh < 2) ? &As[0][0] : &Bs[0][0]) + E;
  }

  // Fragment-read bases; row&7 == ln15&7 (i*16 ≡ 0 mod 8)
  const int rA = wr * 128 + ln15;
  const int rB = wc * 64 + ln15;
  const int sA0 = ((g4 ^ (ln15 & 7)) << 3), sA1 = (((4 | g4) ^ (ln15 & 7)) << 3);
  const bf16_t* pA = &As[0][rA * 64];
  const bf16_t* pB = &Bs[0][rB * 64];

#pragma unroll
  for (int i = 0; i < 8; ++i)
#pragma unroll
    for (int j = 0; j < 4; ++j) acc[i][j] = {0.f, 0.f, 0.f, 0.f};

  // Prologue: stage tile 0 into buf 0, drain, sync.
#pragma unroll
  for (int sl = 0; sl < 8; ++sl) gld_lds16(gsrc[sl], ldst[sl]);
  asm volatile("s_waitcnt vmcnt(0)" ::: "memory");
  __builtin_amdgcn_sched_barrier(0);
  __builtin_amdgcn_s_barrier();
  __builtin_amdgcn_sched_barrier(0);

  bf16x8 afr[8][2], bfr[4][2];

#pragma unroll 2
  for (int kt = 0; kt < 16; ++kt) {
    const int bo = (kt & 1) << 14;               // buf element offset (16384)

    // Stage the whole NEXT tile into buf^1 (8 global_load_lds).
    if (kt + 1 < 16) {
      const int k0n = (kt + 1) << 6;
      const int bon = ((kt + 1) & 1) << 14;
#pragma unroll
      for (int sl = 0; sl < 8; ++sl) gld_lds16(gsrc[sl] + k0n, ldst[sl] + bon);
    }

    // Batch 1: A rows (mh0) + B cols (n01)  -> 12 ds_read_b128
    const bf16_t* pAb = pA + bo;
    const bf16_t* pBb = pB + bo;
#pragma unroll
    for (int i = 0; i < 4; ++i) {
      afr[i][0] = *(const bf16x8*)(pAb + i * 1024 + sA0);
      afr[i][1] = *(const bf16x8*)(pAb + i * 1024 + sA1);
    }
#pragma unroll
    for (int j = 0; j < 2; ++j) {
      bfr[j][0] = *(const bf16x8*)(pBb + j * 1024 + sA0);
      bfr[j][1] = *(const bf16x8*)(pBb + j * 1024 + sA1);
    }

    // q0: mh0 x n01
#pragma unroll
    for (int i = 0; i < 4; ++i)
#pragma unroll
      for (int j = 0; j < 2; ++j) {
        MFMA_B16(afr[i][0], bfr[j][0], acc[i][j]);
        MFMA_B16(afr[i][1], bfr[j][1], acc[i][j]);
      }

    // Batch 2: B cols (n23) + A rows (mh1) -> 12 ds_read_b128 (overlap q0/q1)
#pragma unroll
    for (int j = 2; j < 4; ++j) {
      bfr[j][0] = *(const bf16x8*)(pBb + j * 1024 + sA0);
      bfr[j][1] = *(const bf16x8*)(pBb + j * 1024 + sA1);
    }
#pragma unroll
    for (int i = 4; i < 8; ++i) {
      afr[i][0] = *(const bf16x8*)(pAb + i * 1024 + sA0);
      afr[i][1] = *(const bf16x8*)(pAb + i * 1024 + sA1);
    }

    // q1: mh0 x n23
#pragma unroll
    for (int i = 0; i < 4; ++i)
#pragma unroll
      for (int j = 2; j < 4; ++j) {
        MFMA_B16(afr[i][0], bfr[j][0], acc[i][j]);
        MFMA_B16(afr[i][1], bfr[j][1], acc[i][j]);
      }
    // q2: mh1 x n23
#pragma unroll
    for (int i = 4; i < 8; ++i)
#pragma unroll
      for (int j = 2; j < 4; ++j) {
        MFMA_B16(afr[i][0], bfr[j][0], acc[i][j]);
        MFMA_B16(afr[i][1], bfr[j][1], acc[i][j]);
      }
    // q3: mh1 x n01
#pragma unroll
    for (int i = 4; i < 8; ++i)
#pragma unroll
      for (int j = 0; j < 2; ++j) {
        MFMA_B16(afr[i][0], bfr[j][0], acc[i][j]);
        MFMA_B16(afr[i][1], bfr[j][1], acc[i][j]);
      }

    // Tile end: next tile landed; all waves' reads of buf retired.
    asm volatile("s_waitcnt vmcnt(0)" ::: "memory");
    __builtin_amdgcn_sched_barrier(0);
    __builtin_amdgcn_s_barrier();
    __builtin_amdgcn_sched_barrier(0);
  }
}

// Fused QKV projection: C[32768][3072] = Xbf * Wqkv^T. Segment (1024-col) 0->Q
// head-major, 1->K head-major, 2->Vt transposed layout.
__global__ __launch_bounds__(512, 2)
void gemm_qkv3_k(const bf16_t* __restrict__ A, const bf16_t* __restrict__ Wt,
                 const float* __restrict__ bq, const float* __restrict__ bk,
                 const float* __restrict__ bvv,
                 bf16_t* __restrict__ Qh, bf16_t* __restrict__ Kh,
                 bf16_t* __restrict__ Vt) {
  f32x4 acc[8][4];
  int m0, n0;
  gemm256_core<12>(A, Wt, acc, m0, n0);

  const int tid = threadIdx.x;
  const int wid = tid >> 6, ln = tid & 63;
  const int ln15 = ln & 15, g4 = ln >> 4;
  const int wr = wid >> 2, wc = wid & 3;

  const int seg = n0 >> 10;                      // block-uniform: 0=Q 1=K 2=V
  const float* bias = (seg == 0) ? bq : (seg == 1) ? bk : bvv;
  bf16_t* QK = (seg == 0) ? Qh : Kh;
#pragma unroll
  for (int i = 0; i < 8; ++i) {
    const int rbase = m0 + wr * 128 + i * 16 + g4 * 4;
    const int b = rbase >> 9, pb = rbase & 511;
#pragma unroll
    for (int j = 0; j < 4; ++j) {
      const int col = n0 + wc * 64 + j * 16 + ln15;
      const int cl = col & 1023;
      const int h = cl >> 6, hd = cl & 63;
      const float bv = bias[cl];
      if (seg < 2) {
        // head-major: [b][h][p][hd]
#pragma unroll
        for (int r = 0; r < 4; ++r)
          QK[(((size_t)(b * cH + h)) * cP + pb + r) * cHD + hd] =
              (bf16_t)(acc[i][j][r] + bv);
      } else {
        bf16x4 pk;
#pragma unroll
        for (int r = 0; r < 4; ++r) pk[r] = (bf16_t)(acc[i][j][r] + bv);
        *(bf16x4*)(Vt + ((size_t)((b * cH + h) * cHD + hd)) * cVTP + 128 + pb) = pk;
      }
    }
  }
}

// Output projection: C[32768][1024] fp32 = Ob * Wot^T + bo
__global__ __launch_bounds__(512, 2)
void gemm_bt3_k(const bf16_t* __restrict__ A, const bf16_t* __restrict__ Bt,
                const float* __restrict__ bias, float* __restrict__ C) {
  f32x4 acc[8][4];
  int m0, n0;
  gemm256_core<4>(A, Bt, acc, m0, n0);

  const int tid = threadIdx.x;
  const int wid = tid >> 6, ln = tid & 63;
  const int ln15 = ln & 15, g4 = ln >> 4;
  const int wr = wid >> 2, wc = wid & 3;

#pragma unroll
  for (int i = 0; i < 8; ++i) {
    const int rbase = m0 + wr * 128 + i * 16 + g4 * 4;
#pragma unroll
    for (int j = 0; j < 4; ++j) {
      const int col = n0 + wc * 64 + j * 16 + ln15;
      const float bv = bias[col];
#pragma unroll
      for (int r = 0; r < 4; ++r)
        C[(size_t)(rbase + r) * cD + col] = acc[i][j][r] + bv;
    }
  }
}

// ---------------------------------------------------------------------------
// Windowed attention v4: block = (head, batch, t-chunk); 4 waves each own a
// 16-token tile; 2 subs cover the 128-token chunk. NEW vs v3: the block's
// K-window (rows [tc*128-128, tc*128+128)) is staged into LDS ONCE,
// cooperatively and coalesced (128B segments), OOB rows zero-filled — this
// removes the per-chunk divergent bounds branch and the 16-lane x 16B
// scattered K loads (which were re-read 3-4x across waves from L2).
// K LDS row pad +8 cols: stride 144B ≡ 4 dwords mod 32 banks -> 2-way
// conflict on fragment reads (free per m136). LDS total 58.4 KB -> 2 blk/CU.
__global__ __launch_bounds__(256)
void attn4_k(const bf16_t* __restrict__ Q, const bf16_t* __restrict__ Kv,
             const bf16_t* __restrict__ Vt, const int* __restrict__ rr,
             bf16_t* __restrict__ O) {
  __shared__ __align__(16) bf16_t Ks[256 * 72];
  __shared__ __align__(16) bf16_t Pl[4][16][168];
  const int tid = threadIdx.x;
  const int wv = tid >> 6, ln = tid & 63, ln15 = ln & 15, g4 = ln >> 4;
  const int h = blockIdx.x, b = blockIdx.y, tc = blockIdx.z;
  bf16_t(*Pw)[168] = Pl[wv];
  const bf16_t* vb = Vt + ((size_t)(b * cH + h)) * cHD * cVTP;
  const bf16_t* qb = Q + ((size_t)(b * cH + h)) * cP * cHD;
  const bf16_t* kb = Kv + ((size_t)(b * cH + h)) * cP * cHD;

  // ---- Stage the block's K window: rows kbase..kbase+255, 64 cols ----
  const int kbase = tc * 128 - 128;
#pragma unroll
  for (int p = 0; p < 8; ++p) {
    const int slot = p * 256 + tid;
    const int row = slot >> 3, cg = slot & 7;    // 8 x 16B groups per row
    const int s = kbase + row;
    bf16x8 v;
    if ((unsigned)s < (unsigned)cP) {
      v = *(const bf16x8*)(kb + (size_t)s * cHD + cg * 8);
    } else {
#pragma unroll
      for (int z = 0; z < 8; ++z) v[z] = (bf16_t)0.f;
    }
    *(bf16x8*)(Ks + row * 72 + cg * 8) = v;
  }
  __syncthreads();

  for (int sub = 0; sub < 2; ++sub) {
    const int t0 = (tc * 2 + sub) * 64 + wv * 16;
    const int sbase = t0 - 128;

    int rv[4];
#pragma unroll
    for (int r = 0; r < 4; ++r) rv[r] = rr[b * cP + t0 + g4 * 4 + r];

    // Q A-frag: m = ln15 (t), k = g4*8+j (hd)
    const bf16_t* qp = qb + (size_t)(t0 + ln15) * cHD + g4 * 8;
    const bf16x8 qa0 = *(const bf16x8*)qp;
    const bf16x8 qa1 = *(const bf16x8*)(qp + 32);

    // QK^T over 9 s-chunks of 16, K frags from LDS.
    // LDS row for chunk c = sub*64 + wv*16 + c*16 + ln15  (in [0,256))
    const bf16_t* kls = Ks + (sub * 64 + wv * 16 + ln15) * 72 + g4 * 8;
    f32x4 lg[9];
#pragma unroll
    for (int c = 0; c < 9; ++c) {
      const bf16_t* kp = kls + c * (16 * 72);
      const bf16x8 k0v = *(const bf16x8*)kp;
      const bf16x8 k1v = *(const bf16x8*)(kp + 32);
      f32x4 a = {0.f, 0.f, 0.f, 0.f};
      a = __builtin_amdgcn_mfma_f32_16x16x32_bf16(qa0, k0v, a, 0, 0, 0);
      a = __builtin_amdgcn_mfma_f32_16x16x32_bf16(qa1, k1v, a, 0, 0, 0);
      lg[c] = a;
    }

    // mask + scale; C layout: col(s)=ln15, row(t)=g4*4+reg
    float mx[4] = {-1e30f, -1e30f, -1e30f, -1e30f};
#pragma unroll
    for (int c = 0; c < 9; ++c)
#pragma unroll
      for (int r = 0; r < 4; ++r) {
        const int s = sbase + c * 16 + ln15;
        const int t = t0 + g4 * 4 + r;
        const bool ok = (s >= rv[r]) && (s <= t) && (t - s < cW);
        const float l = ok ? lg[c][r] * cSCALE : -1e30f;
        lg[c][r] = l;
        mx[r] = fmaxf(mx[r], l);
      }
#pragma unroll
    for (int r = 0; r < 4; ++r) {
      mx[r] = fmaxf(mx[r], __shfl_xor(mx[r], 1));
      mx[r] = fmaxf(mx[r], __shfl_xor(mx[r], 2));
      mx[r] = fmaxf(mx[r], __shfl_xor(mx[r], 4));
      mx[r] = fmaxf(mx[r], __shfl_xor(mx[r], 8));
    }
    float sm[4] = {0.f, 0.f, 0.f, 0.f};
#pragma unroll
    for (int c = 0; c < 9; ++c)
#pragma unroll
      for (int r = 0; r < 4; ++r) {
        const float e = __expf(lg[c][r] - mx[r]);
        lg[c][r] = e;
        sm[r] += e;
      }
#pragma unroll
    for (int r = 0; r < 4; ++r) {
      sm[r] += __shfl_xor(sm[r], 1);
      sm[r] += __shfl_xor(sm[r], 2);
      sm[r] += __shfl_xor(sm[r], 4);
      sm[r] += __shfl_xor(sm[r], 8);
    }
    float inv[4];
#pragma unroll
    for (int r = 0; r < 4; ++r) inv[r] = 1.f / sm[r];

    // P -> LDS (C-layout write), zero pad cols 144..159 for the 5th PV chunk
#pragma unroll
    for (int c = 0; c < 9; ++c)
#pragma unroll
      for (int r = 0; r < 4; ++r)
        Pw[g4 * 4 + r][c * 16 + ln15] = (bf16_t)(lg[c][r] * inv[r]);
#pragma unroll
    for (int z = 0; z < 4; ++z)
      Pw[ln15][144 + g4 * 4 + z] = (bf16_t)0.f;

    // PV: A = P (m=t, k=s from LDS), B = Vt rows (n=hd, k=s contiguous)
    f32x4 oacc[4];
#pragma unroll
    for (int j = 0; j < 4; ++j) oacc[j] = {0.f, 0.f, 0.f, 0.f};
#pragma unroll
    for (int c2 = 0; c2 < 5; ++c2) {
      const bf16x8 pa = *(const bf16x8*)(&Pw[ln15][c2 * 32 + g4 * 8]);
#pragma unroll
      for (int j = 0; j < 4; ++j) {
        const bf16x8 vf =
            *(const bf16x8*)(vb + (size_t)(j * 16 + ln15) * cVTP + (t0 + c2 * 32 + g4 * 8));
        oacc[j] = __builtin_amdgcn_mfma_f32_16x16x32_bf16(pa, vf, oacc[j], 0, 0, 0);
      }
    }
#pragma unroll
    for (int j = 0; j < 4; ++j) {
      const int col = h * cHD + j * 16 + ln15;
#pragma unroll
      for (int r = 0; r < 4; ++r)
        O[((size_t)(b * cP + t0 + g4 * 4 + r)) * cDWM + col] = (bf16_t)oacc[j][r];
    }
  }
}

// ---------------------------------------------------------------------------
extern "C" void kernel_launch(void* const* d_in, const int* in_sizes, int n_in,
                              void* d_out, int out_size, void* d_ws, size_t ws_size,
                              hipStream_t stream) {
  (void)in_sizes; (void)n_in; (void)out_size; (void)ws_size;
  const float* x  = (const float*)d_in[0];
  const int* mask = (const int*)d_in[1];
  const float* Wq = (const float*)d_in[2];
  const float* bq = (const float*)d_in[3];
  const float* Wk = (const float*)d_in[4];
  const float* bk = (const float*)d_in[5];
  const float* Wv = (const float*)d_in[6];
  const float* bv = (const float*)d_in[7];
  const float* Wo = (const float*)d_in[8];
  const float* bo = (const float*)d_in[9];
  float* out = (float*)d_out;

  char* ws = (char*)d_ws;
  size_t off = 0;
  bf16_t* Xbf = (bf16_t*)(ws + off); off += (size_t)cM * cD * 2;          // 64 MiB
  bf16_t* Wqt = (bf16_t*)(ws + off); off += (size_t)cD * cDWM * 2;        // contiguous
  bf16_t* Wkt = (bf16_t*)(ws + off); off += (size_t)cD * cDWM * 2;        //   [3072][1024]
  bf16_t* Wvt = (bf16_t*)(ws + off); off += (size_t)cD * cDWM * 2;        //   QKV block
  bf16_t* Wot = (bf16_t*)(ws + off); off += (size_t)cDWM * cD * 2;
  bf16_t* Qh  = (bf16_t*)(ws + off); off += (size_t)cM * cDWM * 2;        // 64 MiB
  bf16_t* Kh  = (bf16_t*)(ws + off); off += (size_t)cM * cDWM * 2;        // 64 MiB
  bf16_t* Vt  = (bf16_t*)(ws + off); off += (size_t)cBS * cH * cHD * cVTP * 2;  // 84 MiB
  int* rbuf   = (int*)(ws + off);    off += (size_t)cBS * cP * 4;
  bf16_t* Ob  = Xbf;  // X no longer needed after the QKV projection

  cvt_x_k<<<(cM * cD / 4 + 255) / 256, 256, 0, stream>>>(x, Xbf, cM * cD);
  cvt_wt_k<<<dim3(32, 32, 4), 256, 0, stream>>>(Wq, Wk, Wv, Wo, Wqt, Wkt, Wvt, Wot);
  resets2_k<<<cBS, cP, 0, stream>>>(mask, rbuf);

  // 8 XCD x 16 m-blocks x 12 n-blocks = 1536 workgroups of 512
  gemm_qkv3_k<<<dim3(1536), 512, 0, stream>>>(Xbf, Wqt, bq, bk, bv, Qh, Kh, Vt);

  attn4_k<<<dim3(cH, cBS, 4), 256, 0, stream>>>(Qh, Kh, Vt, rbuf, Ob);

  // 8 XCD x 16 m-blocks x 4 n-blocks = 512 workgroups of 512
  gemm_bt3_k<<<dim3(512), 512, 0, stream>>>(Ob, Wot, bo, out);
}

// Round 5
// 658.125 us; speedup vs baseline: 1.2881x; 1.0717x over previous
//
#include <hip/hip_runtime.h>
#include <stdint.h>

typedef __bf16 bf16_t;
typedef __bf16 bf16x8 __attribute__((ext_vector_type(8)));
typedef __bf16 bf16x4 __attribute__((ext_vector_type(4)));
typedef float  f32x4  __attribute__((ext_vector_type(4)));

constexpr int cBS = 64, cP = 512, cD = 1024, cDWM = 1024, cH = 16, cHD = 64, cW = 128;
constexpr int cVTP = 672;           // padded p-extent of Vt (sp = p + 128, max used 656)
constexpr int cM = cBS * cP;        // 32768
constexpr float cSCALE = 0.125f;    // 1/sqrt(64)

__device__ __forceinline__ void gld_lds16(const void* g, void* l) {
#if __has_builtin(__builtin_amdgcn_global_load_lds)
  __builtin_amdgcn_global_load_lds(
      (__attribute__((address_space(1))) void*)g,
      (__attribute__((address_space(3))) void*)l, 16, 0, 0);
#else
  *(bf16x8*)l = *(const bf16x8*)g;
#endif
}

// ---------------------------------------------------------------------------
// fp32 -> bf16 conversion of X
__global__ void cvt_x_k(const float* __restrict__ X, bf16_t* __restrict__ Y, int n) {
  int i = (blockIdx.x * blockDim.x + threadIdx.x) * 4;
  if (i >= n) return;
  float4 v = *(const float4*)(X + i);
  bf16x4 o;
  o[0] = (bf16_t)v.x; o[1] = (bf16_t)v.y; o[2] = (bf16_t)v.z; o[3] = (bf16_t)v.w;
  *(bf16x4*)(Y + i) = o;
}

// transpose + convert the four 1024x1024 weights: W[k][n] fp32 -> Wt[n][k] bf16
__global__ void cvt_wt_k(const float* __restrict__ W0, const float* __restrict__ W1,
                         const float* __restrict__ W2, const float* __restrict__ W3,
                         bf16_t* __restrict__ T0, bf16_t* __restrict__ T1,
                         bf16_t* __restrict__ T2, bf16_t* __restrict__ T3) {
  __shared__ float tile[32][33];
  const float* Wsrc; bf16_t* Tdst;
  switch (blockIdx.z) {
    case 0: Wsrc = W0; Tdst = T0; break;
    case 1: Wsrc = W1; Tdst = T1; break;
    case 2: Wsrc = W2; Tdst = T2; break;
    default: Wsrc = W3; Tdst = T3; break;
  }
  const int n0 = blockIdx.x * 32, k0 = blockIdx.y * 32;
  const int c = threadIdx.x & 31, r8 = threadIdx.x >> 5;
#pragma unroll
  for (int q = 0; q < 4; ++q) {
    int row = r8 + q * 8;
    tile[row][c] = Wsrc[(size_t)(k0 + row) * 1024 + n0 + c];
  }
  __syncthreads();
#pragma unroll
  for (int q = 0; q < 4; ++q) {
    int row = r8 + q * 8;
    Tdst[(size_t)(n0 + row) * 1024 + k0 + c] = (bf16_t)tile[c][row];
  }
}

// r[b][t] = index of last reset at-or-before t (0 if none): parallel max-scan
__global__ void resets2_k(const int* __restrict__ mask, int* __restrict__ r) {
  __shared__ int sm[cP];
  const int b = blockIdx.x, t = threadIdx.x;
  sm[t] = mask[b * cP + t] ? t : 0;
  __syncthreads();
#pragma unroll
  for (int d = 1; d < cP; d <<= 1) {
    int u = (t >= d) ? sm[t - d] : 0;
    __syncthreads();
    if (u > sm[t]) sm[t] = u;
    __syncthreads();
  }
  r[b * cP + t] = sm[t];
}

// ---------------------------------------------------------------------------
// 256x256 GEMM core (r2 version — measured 264 us on the fused QKV shape):
//   BM=BN=256, BK=64, 512 threads = 8 waves (2Mx4N), per-wave 128x64 out.
//   ONE barrier per K-tile; whole next tile prefetched into buf^1 (depth-1);
//   fragment reads in two batches interleaved with MFMA quadrants; compiler
//   inserts counted lgkmcnt waits. LDS XOR swizzle: bank-conflict-free.
#define MFMA_B16(a, b, c) c = __builtin_amdgcn_mfma_f32_16x16x32_bf16(a, b, c, 0, 0, 0)

template <int NBLK>
__device__ __forceinline__ void gemm256_core(const bf16_t* __restrict__ A,
                                             const bf16_t* __restrict__ Bt,
                                             f32x4 (&acc)[8][4],
                                             int& m0_out, int& n0_out) {
  constexpr int K = 1024;
  __shared__ __align__(16) bf16_t As[2][256 * 64];
  __shared__ __align__(16) bf16_t Bs[2][256 * 64];
  const int tid = threadIdx.x;
  const int wid = tid >> 6, ln = tid & 63;
  const int ln15 = ln & 15, g4 = ln >> 4;
  const int wr = wid >> 2, wc = wid & 3;

  // XCD-aware swizzle: grid = 8 XCDs x 16 m-blocks x NBLK n-blocks, n-fastest
  const int g = blockIdx.x;
  const int xcd = g & 7, s = g >> 3;
  const int nb = s % NBLK, mloc = s / NBLK;
  const int m0 = (xcd * 16 + mloc) * 256, n0 = nb * 256;
  m0_out = m0; n0_out = n0;

  const bf16_t* Ag = A + (size_t)m0 * K;
  const bf16_t* Bg = Bt + (size_t)n0 * K;

  // Stage addressing: 8 (half,l) slots; LDS dest linear (global_load_lds
  // rule), swizzle applied on the per-lane GLOBAL source group.
  const bf16_t* gsrc[8];
  bf16_t* ldst[8];
#pragma unroll
  for (int sl = 0; sl < 8; ++sl) {
    const int hh = sl >> 1, l = sl & 1;
    const int E = ((hh & 1) << 13) | (l << 12) | (tid << 3);
    const int row = E >> 6;
    const int cg = ((E >> 3) & 7) ^ (row & 7);
    gsrc[sl] = ((hh < 2) ? Ag : Bg) + (size_t)row * K + cg * 8;
    ldst[sl] = ((hh < 2) ? &As[0][0] : &Bs[0][0]) + E;
  }

  // Fragment-read bases; row&7 == ln15&7 (i*16 ≡ 0 mod 8)
  const int rA = wr * 128 + ln15;
  const int rB = wc * 64 + ln15;
  const int sA0 = ((g4 ^ (ln15 & 7)) << 3), sA1 = (((4 | g4) ^ (ln15 & 7)) << 3);
  const bf16_t* pA = &As[0][rA * 64];
  const bf16_t* pB = &Bs[0][rB * 64];

#pragma unroll
  for (int i = 0; i < 8; ++i)
#pragma unroll
    for (int j = 0; j < 4; ++j) acc[i][j] = {0.f, 0.f, 0.f, 0.f};

  // Prologue: stage tile 0 into buf 0, drain, sync.
#pragma unroll
  for (int sl = 0; sl < 8; ++sl) gld_lds16(gsrc[sl], ldst[sl]);
  asm volatile("s_waitcnt vmcnt(0)" ::: "memory");
  __builtin_amdgcn_sched_barrier(0);
  __builtin_amdgcn_s_barrier();
  __builtin_amdgcn_sched_barrier(0);

  bf16x8 afr[8][2], bfr[4][2];

#pragma unroll 2
  for (int kt = 0; kt < 16; ++kt) {
    const int bo = (kt & 1) << 14;               // buf element offset (16384)

    // Stage the whole NEXT tile into buf^1 (8 global_load_lds).
    if (kt + 1 < 16) {
      const int k0n = (kt + 1) << 6;
      const int bon = ((kt + 1) & 1) << 14;
#pragma unroll
      for (int sl = 0; sl < 8; ++sl) gld_lds16(gsrc[sl] + k0n, ldst[sl] + bon);
    }

    // Batch 1: A rows (mh0) + B cols (n01)  -> 12 ds_read_b128
    const bf16_t* pAb = pA + bo;
    const bf16_t* pBb = pB + bo;
#pragma unroll
    for (int i = 0; i < 4; ++i) {
      afr[i][0] = *(const bf16x8*)(pAb + i * 1024 + sA0);
      afr[i][1] = *(const bf16x8*)(pAb + i * 1024 + sA1);
    }
#pragma unroll
    for (int j = 0; j < 2; ++j) {
      bfr[j][0] = *(const bf16x8*)(pBb + j * 1024 + sA0);
      bfr[j][1] = *(const bf16x8*)(pBb + j * 1024 + sA1);
    }

    // q0: mh0 x n01
#pragma unroll
    for (int i = 0; i < 4; ++i)
#pragma unroll
      for (int j = 0; j < 2; ++j) {
        MFMA_B16(afr[i][0], bfr[j][0], acc[i][j]);
        MFMA_B16(afr[i][1], bfr[j][1], acc[i][j]);
      }

    // Batch 2: B cols (n23) + A rows (mh1) -> 12 ds_read_b128 (overlap q0/q1)
#pragma unroll
    for (int j = 2; j < 4; ++j) {
      bfr[j][0] = *(const bf16x8*)(pBb + j * 1024 + sA0);
      bfr[j][1] = *(const bf16x8*)(pBb + j * 1024 + sA1);
    }
#pragma unroll
    for (int i = 4; i < 8; ++i) {
      afr[i][0] = *(const bf16x8*)(pAb + i * 1024 + sA0);
      afr[i][1] = *(const bf16x8*)(pAb + i * 1024 + sA1);
    }

    // q1: mh0 x n23
#pragma unroll
    for (int i = 0; i < 4; ++i)
#pragma unroll
      for (int j = 2; j < 4; ++j) {
        MFMA_B16(afr[i][0], bfr[j][0], acc[i][j]);
        MFMA_B16(afr[i][1], bfr[j][1], acc[i][j]);
      }
    // q2: mh1 x n23
#pragma unroll
    for (int i = 4; i < 8; ++i)
#pragma unroll
      for (int j = 2; j < 4; ++j) {
        MFMA_B16(afr[i][0], bfr[j][0], acc[i][j]);
        MFMA_B16(afr[i][1], bfr[j][1], acc[i][j]);
      }
    // q3: mh1 x n01
#pragma unroll
    for (int i = 4; i < 8; ++i)
#pragma unroll
      for (int j = 0; j < 2; ++j) {
        MFMA_B16(afr[i][0], bfr[j][0], acc[i][j]);
        MFMA_B16(afr[i][1], bfr[j][1], acc[i][j]);
      }

    // Tile end: next tile landed; all waves' reads of buf retired.
    asm volatile("s_waitcnt vmcnt(0)" ::: "memory");
    __builtin_amdgcn_sched_barrier(0);
    __builtin_amdgcn_s_barrier();
    __builtin_amdgcn_sched_barrier(0);
  }
}

// One segment of the QKV projection: C[32768][1024] = Xbf * Wt_seg^T.
// seg 0 -> Q head-major, 1 -> K head-major, 2 -> Vt transposed layout.
// Split into 3 launches so B (2 MiB) is L2-resident per XCD and so the
// attention kernel surfaces in the profiler's top-5.
__global__ __launch_bounds__(512, 2)
void gemm_qkvs_k(const bf16_t* __restrict__ A, const bf16_t* __restrict__ Wt,
                 const float* __restrict__ bias,
                 bf16_t* __restrict__ QK, bf16_t* __restrict__ Vt, int seg) {
  f32x4 acc[8][4];
  int m0, n0;
  gemm256_core<4>(A, Wt, acc, m0, n0);

  const int tid = threadIdx.x;
  const int wid = tid >> 6, ln = tid & 63;
  const int ln15 = ln & 15, g4 = ln >> 4;
  const int wr = wid >> 2, wc = wid & 3;

#pragma unroll
  for (int i = 0; i < 8; ++i) {
    const int rbase = m0 + wr * 128 + i * 16 + g4 * 4;
    const int b = rbase >> 9, pb = rbase & 511;
#pragma unroll
    for (int j = 0; j < 4; ++j) {
      const int cl = n0 + wc * 64 + j * 16 + ln15;   // [0,1024)
      const int h = cl >> 6, hd = cl & 63;
      const float bv = bias[cl];
      if (seg < 2) {
        // head-major: [b][h][p][hd]
#pragma unroll
        for (int r = 0; r < 4; ++r)
          QK[(((size_t)(b * cH + h)) * cP + pb + r) * cHD + hd] =
              (bf16_t)(acc[i][j][r] + bv);
      } else {
        bf16x4 pk;
#pragma unroll
        for (int r = 0; r < 4; ++r) pk[r] = (bf16_t)(acc[i][j][r] + bv);
        *(bf16x4*)(Vt + ((size_t)((b * cH + h) * cHD + hd)) * cVTP + 128 + pb) = pk;
      }
    }
  }
}

// Output projection: C[32768][1024] fp32 = Ob * Wot^T + bo
__global__ __launch_bounds__(512, 2)
void gemm_bt3_k(const bf16_t* __restrict__ A, const bf16_t* __restrict__ Bt,
                const float* __restrict__ bias, float* __restrict__ C) {
  f32x4 acc[8][4];
  int m0, n0;
  gemm256_core<4>(A, Bt, acc, m0, n0);

  const int tid = threadIdx.x;
  const int wid = tid >> 6, ln = tid & 63;
  const int ln15 = ln & 15, g4 = ln >> 4;
  const int wr = wid >> 2, wc = wid & 3;

#pragma unroll
  for (int i = 0; i < 8; ++i) {
    const int rbase = m0 + wr * 128 + i * 16 + g4 * 4;
#pragma unroll
    for (int j = 0; j < 4; ++j) {
      const int col = n0 + wc * 64 + j * 16 + ln15;
      const float bv = bias[col];
#pragma unroll
      for (int r = 0; r < 4; ++r)
        C[(size_t)(rbase + r) * cD + col] = acc[i][j][r] + bv;
    }
  }
}

// ---------------------------------------------------------------------------
// Windowed attention v5: as v4 (K window staged once per block, coalesced),
// plus: rr via one int4 load; PV restructured j-outer with all 5 P-fragments
// and 5 V-fragments preloaded per j (5-deep global-load ILP instead of a
// 1-deep load->MFMA latency chain).
__global__ __launch_bounds__(256)
void attn5_k(const bf16_t* __restrict__ Q, const bf16_t* __restrict__ Kv,
             const bf16_t* __restrict__ Vt, const int* __restrict__ rr,
             bf16_t* __restrict__ O) {
  __shared__ __align__(16) bf16_t Ks[256 * 72];
  __shared__ __align__(16) bf16_t Pl[4][16][168];
  const int tid = threadIdx.x;
  const int wv = tid >> 6, ln = tid & 63, ln15 = ln & 15, g4 = ln >> 4;
  const int h = blockIdx.x, b = blockIdx.y, tc = blockIdx.z;
  bf16_t(*Pw)[168] = Pl[wv];
  const bf16_t* vb = Vt + ((size_t)(b * cH + h)) * cHD * cVTP;
  const bf16_t* qb = Q + ((size_t)(b * cH + h)) * cP * cHD;
  const bf16_t* kb = Kv + ((size_t)(b * cH + h)) * cP * cHD;

  // ---- Stage the block's K window: rows kbase..kbase+255, 64 cols ----
  const int kbase = tc * 128 - 128;
#pragma unroll
  for (int p = 0; p < 8; ++p) {
    const int slot = p * 256 + tid;
    const int row = slot >> 3, cg = slot & 7;    // 8 x 16B groups per row
    const int s = kbase + row;
    bf16x8 v;
    if ((unsigned)s < (unsigned)cP) {
      v = *(const bf16x8*)(kb + (size_t)s * cHD + cg * 8);
    } else {
#pragma unroll
      for (int z = 0; z < 8; ++z) v[z] = (bf16_t)0.f;
    }
    *(bf16x8*)(Ks + row * 72 + cg * 8) = v;
  }
  __syncthreads();

  for (int sub = 0; sub < 2; ++sub) {
    const int t0 = (tc * 2 + sub) * 64 + wv * 16;
    const int sbase = t0 - 128;

    const int4 rvv = *(const int4*)(rr + b * cP + t0 + g4 * 4);
    const int rv[4] = {rvv.x, rvv.y, rvv.z, rvv.w};

    // Q A-frag: m = ln15 (t), k = g4*8+j (hd)
    const bf16_t* qp = qb + (size_t)(t0 + ln15) * cHD + g4 * 8;
    const bf16x8 qa0 = *(const bf16x8*)qp;
    const bf16x8 qa1 = *(const bf16x8*)(qp + 32);

    // QK^T over 9 s-chunks of 16, K frags from LDS.
    const bf16_t* kls = Ks + (sub * 64 + wv * 16 + ln15) * 72 + g4 * 8;
    f32x4 lg[9];
#pragma unroll
    for (int c = 0; c < 9; ++c) {
      const bf16_t* kp = kls + c * (16 * 72);
      const bf16x8 k0v = *(const bf16x8*)kp;
      const bf16x8 k1v = *(const bf16x8*)(kp + 32);
      f32x4 a = {0.f, 0.f, 0.f, 0.f};
      a = __builtin_amdgcn_mfma_f32_16x16x32_bf16(qa0, k0v, a, 0, 0, 0);
      a = __builtin_amdgcn_mfma_f32_16x16x32_bf16(qa1, k1v, a, 0, 0, 0);
      lg[c] = a;
    }

    // mask + scale; C layout: col(s)=ln15, row(t)=g4*4+reg
    float mx[4] = {-1e30f, -1e30f, -1e30f, -1e30f};
#pragma unroll
    for (int c = 0; c < 9; ++c)
#pragma unroll
      for (int r = 0; r < 4; ++r) {
        const int s = sbase + c * 16 + ln15;
        const int t = t0 + g4 * 4 + r;
        const bool ok = (s >= rv[r]) && (s <= t) && (t - s < cW);
        const float l = ok ? lg[c][r] * cSCALE : -1e30f;
        lg[c][r] = l;
        mx[r] = fmaxf(mx[r], l);
      }
#pragma unroll
    for (int r = 0; r < 4; ++r) {
      mx[r] = fmaxf(mx[r], __shfl_xor(mx[r], 1));
      mx[r] = fmaxf(mx[r], __shfl_xor(mx[r], 2));
      mx[r] = fmaxf(mx[r], __shfl_xor(mx[r], 4));
      mx[r] = fmaxf(mx[r], __shfl_xor(mx[r], 8));
    }
    float sm[4] = {0.f, 0.f, 0.f, 0.f};
#pragma unroll
    for (int c = 0; c < 9; ++c)
#pragma unroll
      for (int r = 0; r < 4; ++r) {
        const float e = __expf(lg[c][r] - mx[r]);
        lg[c][r] = e;
        sm[r] += e;
      }
#pragma unroll
    for (int r = 0; r < 4; ++r) {
      sm[r] += __shfl_xor(sm[r], 1);
      sm[r] += __shfl_xor(sm[r], 2);
      sm[r] += __shfl_xor(sm[r], 4);
      sm[r] += __shfl_xor(sm[r], 8);
    }
    float inv[4];
#pragma unroll
    for (int r = 0; r < 4; ++r) inv[r] = 1.f / sm[r];

    // P -> LDS (C-layout write), zero pad cols 144..159 for the 5th PV chunk
#pragma unroll
    for (int c = 0; c < 9; ++c)
#pragma unroll
      for (int r = 0; r < 4; ++r)
        Pw[g4 * 4 + r][c * 16 + ln15] = (bf16_t)(lg[c][r] * inv[r]);
#pragma unroll
    for (int z = 0; z < 4; ++z)
      Pw[ln15][144 + g4 * 4 + z] = (bf16_t)0.f;

    // PV: A = P (m=t, k=s from LDS), B = Vt rows (n=hd, k=s contiguous).
    // Preload all 5 P-frags; per j preload 5 V-frags, then 5 chained MFMAs.
    bf16x8 paf[5];
#pragma unroll
    for (int c2 = 0; c2 < 5; ++c2)
      paf[c2] = *(const bf16x8*)(&Pw[ln15][c2 * 32 + g4 * 8]);

    f32x4 oacc[4];
#pragma unroll
    for (int j = 0; j < 4; ++j) {
      const bf16_t* vrow = vb + (size_t)(j * 16 + ln15) * cVTP + t0 + g4 * 8;
      bf16x8 vf[5];
#pragma unroll
      for (int c2 = 0; c2 < 5; ++c2) vf[c2] = *(const bf16x8*)(vrow + c2 * 32);
      f32x4 a = {0.f, 0.f, 0.f, 0.f};
#pragma unroll
      for (int c2 = 0; c2 < 5; ++c2)
        a = __builtin_amdgcn_mfma_f32_16x16x32_bf16(paf[c2], vf[c2], a, 0, 0, 0);
      oacc[j] = a;
    }
#pragma unroll
    for (int j = 0; j < 4; ++j) {
      const int col = h * cHD + j * 16 + ln15;
#pragma unroll
      for (int r = 0; r < 4; ++r)
        O[((size_t)(b * cP + t0 + g4 * 4 + r)) * cDWM + col] = (bf16_t)oacc[j][r];
    }
  }
}

// ---------------------------------------------------------------------------
extern "C" void kernel_launch(void* const* d_in, const int* in_sizes, int n_in,
                              void* d_out, int out_size, void* d_ws, size_t ws_size,
                              hipStream_t stream) {
  (void)in_sizes; (void)n_in; (void)out_size; (void)ws_size;
  const float* x  = (const float*)d_in[0];
  const int* mask = (const int*)d_in[1];
  const float* Wq = (const float*)d_in[2];
  const float* bq = (const float*)d_in[3];
  const float* Wk = (const float*)d_in[4];
  const float* bk = (const float*)d_in[5];
  const float* Wv = (const float*)d_in[6];
  const float* bv = (const float*)d_in[7];
  const float* Wo = (const float*)d_in[8];
  const float* bo = (const float*)d_in[9];
  float* out = (float*)d_out;

  char* ws = (char*)d_ws;
  size_t off = 0;
  bf16_t* Xbf = (bf16_t*)(ws + off); off += (size_t)cM * cD * 2;          // 64 MiB
  bf16_t* Wqt = (bf16_t*)(ws + off); off += (size_t)cD * cDWM * 2;
  bf16_t* Wkt = (bf16_t*)(ws + off); off += (size_t)cD * cDWM * 2;
  bf16_t* Wvt = (bf16_t*)(ws + off); off += (size_t)cD * cDWM * 2;
  bf16_t* Wot = (bf16_t*)(ws + off); off += (size_t)cDWM * cD * 2;
  bf16_t* Qh  = (bf16_t*)(ws + off); off += (size_t)cM * cDWM * 2;        // 64 MiB
  bf16_t* Kh  = (bf16_t*)(ws + off); off += (size_t)cM * cDWM * 2;        // 64 MiB
  bf16_t* Vt  = (bf16_t*)(ws + off); off += (size_t)cBS * cH * cHD * cVTP * 2;  // 84 MiB
  int* rbuf   = (int*)(ws + off);    off += (size_t)cBS * cP * 4;
  bf16_t* Ob  = Xbf;  // X no longer needed after the QKV projection

  cvt_x_k<<<(cM * cD / 4 + 255) / 256, 256, 0, stream>>>(x, Xbf, cM * cD);
  cvt_wt_k<<<dim3(32, 32, 4), 256, 0, stream>>>(Wq, Wk, Wv, Wo, Wqt, Wkt, Wvt, Wot);
  resets2_k<<<cBS, cP, 0, stream>>>(mask, rbuf);

  // QKV as 3 launches of 512 workgroups (B = 2 MiB, L2-resident per XCD)
  gemm_qkvs_k<<<dim3(512), 512, 0, stream>>>(Xbf, Wqt, bq, Qh, Vt, 0);
  gemm_qkvs_k<<<dim3(512), 512, 0, stream>>>(Xbf, Wkt, bk, Kh, Vt, 1);
  gemm_qkvs_k<<<dim3(512), 512, 0, stream>>>(Xbf, Wvt, bv, Qh, Vt, 2);

  attn5_k<<<dim3(cH, cBS, 4), 256, 0, stream>>>(Qh, Kh, Vt, rbuf, Ob);

  // 8 XCD x 16 m-blocks x 4 n-blocks = 512 workgroups of 512
  gemm_bt3_k<<<dim3(512), 512, 0, stream>>>(Ob, Wot, bo, out);
}